// Round 17
// baseline (132.643 us; speedup 1.0000x reference)
//
#include <hip/hip_runtime.h>

#define MDIM 512
#define NDIM 8192
#define KDIM 8192

typedef float v4f __attribute__((ext_vector_type(4)));
typedef int   v4i __attribute__((ext_vector_type(4)));
typedef char  c16 __attribute__((ext_vector_type(16)));

#define GLDS16(g, l)                                                    \
  __builtin_amdgcn_global_load_lds(                                     \
      (const __attribute__((address_space(1))) void*)(g),               \
      (__attribute__((address_space(3))) void*)(l), 16, 0, 0)
#define SB __builtin_amdgcn_sched_barrier(0)

// r8 swizzle: byte offset in a 64-row x 64k int8 tile (4KB), 0 conflicts.
// Producers write it; glds copies linearly; gemm ds_read applies it.
__device__ __forceinline__ int swb(int row, int g) {
  return ((row >> 1) << 7) + (((((row & 1) << 2) | g) ^ ((row >> 1) & 7)) << 4);
}

// Merged producer (r14 exact):
//  blocks [0,16384): wq int32 -> int8, w8 tiles [ntile64(128)][kt64(128)][4KB].
//  blocks [16384,16896): x fp32 -> int8 + per-row scale ax,
//                        xq tiles [mtile64(8)][kt64(128)][4KB].
__global__ __launch_bounds__(256) void produce_kernel(
    const int* __restrict__ wq, const float* __restrict__ x,
    char* __restrict__ w8, char* __restrict__ xq, float* __restrict__ ax) {
  if (blockIdx.x < 16384) {
    const int tid = blockIdx.x * 256 + threadIdx.x;
    const int R = tid >> 9;     // weight row 0..8191
    const int k16 = tid & 511;  // 16-int group
    const int* src = wq + ((size_t)R << 13) + k16 * 16;
    v4i a[4];
#pragma unroll
    for (int h = 0; h < 4; ++h) a[h] = *(const v4i*)(src + h * 4);
    c16 q;
#pragma unroll
    for (int h = 0; h < 4; ++h) {
      q[h * 4 + 0] = (char)a[h][0];
      q[h * 4 + 1] = (char)a[h][1];
      q[h * 4 + 2] = (char)a[h][2];
      q[h * 4 + 3] = (char)a[h][3];
    }
    const int ntile = R >> 6, r = R & 63;
    const int kt = k16 >> 2, g = k16 & 3;
    *(c16*)(w8 + ((size_t)(ntile * 128 + kt) << 12) + swb(r, g)) = q;
  } else {
    const int m = blockIdx.x - 16384;
    const int t = threadIdx.x;
    const float* row = x + ((size_t)m << 13);
    v4f v[8];
    float mx = 0.f;
#pragma unroll
    for (int i = 0; i < 8; ++i) {
      v[i] = *(const v4f*)(row + t * 32 + i * 4);
#pragma unroll
      for (int r = 0; r < 4; ++r) mx = fmaxf(mx, fabsf(v[i][r]));
    }
#pragma unroll
    for (int d = 1; d < 64; d <<= 1) mx = fmaxf(mx, __shfl_xor(mx, d));
    __shared__ float smx[4];
    if ((t & 63) == 0) smx[t >> 6] = mx;
    __syncthreads();
    mx = fmaxf(fmaxf(smx[0], smx[1]), fmaxf(smx[2], smx[3]));
    const float inv = (mx > 0.f) ? 127.f / mx : 0.f;
    if (t == 0) ax[m] = mx / 127.f;
    const int mt = m >> 6, r = m & 63;  // 64-row xq tiles
#pragma unroll
    for (int g2 = 0; g2 < 2; ++g2) {
      c16 q;
#pragma unroll
      for (int e = 0; e < 16; ++e) {
        const int idx = g2 * 4 + (e >> 2);
        float f = fminf(fmaxf(v[idx][e & 3] * inv, -127.f), 127.f);
        q[e] = (char)__float2int_rn(f);
      }
      const int k16 = t * 2 + g2;
      const int kt = k16 >> 2, g = k16 & 3;
      *(c16*)(xq + ((size_t)(mt * 128 + kt) << 12) + swb(r, g)) = q;
    }
  }
}

template <int KS>
__global__ __launch_bounds__(256) void reduce_kernel(const float* __restrict__ p,
                                                     float* __restrict__ out) {
  const size_t i = ((size_t)blockIdx.x * 256 + threadIdx.x) * 4;
  v4f a = *(const v4f*)(p + i);
#pragma unroll
  for (int s = 1; s < KS; ++s) a += *(const v4f*)(p + (size_t)s * MDIM * NDIM + i);
  *(v4f*)(out + i) = a;
}

// Deep-pipelined i8 GEMM (T3+T4 port): BM=256, BN=128, BK=128, 8 waves
// (wave tile 64x64), TRIPLE-buffered LDS (3 x 48KB), stage lead = 2
// K-tiles, uniform counted vmcnt(6) (never drained mid-loop). Per phase:
// 8 ds_read_b128 + 3 glds + lgkm0 + setprio(1) + 16 MFMA + setprio(0);
// 2 phases (k64 halves) per K-tile; scale-fold per K-tile (k128 block).
// Derived waits: 3 glds/wave/phase -> 12 in flight at iter head; oldest 6
// = the K-tile this iter reads -> vmcnt(6); last iter drains with vmcnt(0).
template <int KS>
__global__ __launch_bounds__(512, 1) void gemm_i8_kernel(
    const char* __restrict__ xq, const char* __restrict__ w8,
    const float* __restrict__ wsc, const float* __restrict__ ax,
    float* __restrict__ outp) {
  constexpr int NKT = 64 / KS;       // k128-tiles per block
  __shared__ char lds[3][49152];     // [buf][A 32KB | B 16KB]

  // XCD swizzle: XCD c owns nt in [c*8, c*8+8) x all mt,kh.
  const int b = blockIdx.x;
  const int c = b & 7;
  const int s = b >> 3;
  const int mt = s & 1;                      // m-tile of 256
  const int kh = (s >> 1) & (KS - 1);
  const int nt = c * 8 + s / (2 * KS);       // n-tile of 128 (0..63)
  const int k64b = kh * (NKT * 2);           // global k64-tile base

  const int t = threadIdx.x;
  const int w = t >> 6, l = t & 63;
  const int wm = (w >> 1) * 64;  // 4 m-strips
  const int wn = (w & 1) * 64;   // 2 n-strips
  const int l15 = l & 15, q = l >> 4;

  v4i acc[4][4] = {};
  v4f facc[4][4] = {};

  // stage half h of K-tile t2 into buffer tb: 3 glds/wave (24 x 1KB units:
  // h=0 -> units 0..23, h=1 -> 24..47; A = units 0..31, B = 32..47)
  auto stage_half = [&](int t2, int tb, int h) {
#pragma unroll
    for (int j = 0; j < 3; ++j) {
      const int u = h * 24 + w * 3 + j;
      if (u < 32) {
        const int sub = u >> 2, qt = u & 3;
        const int rb = sub >> 1, kt = sub & 1;
        const char* src =
            xq + ((size_t)((mt * 4 + rb) * 128 + k64b + t2 * 2 + kt) << 12) +
            qt * 1024 + (size_t)l * 16;
        GLDS16(src, &lds[tb][(rb * 2 + kt) * 4096 + qt * 1024]);
      } else {
        const int v = u - 32;
        const int sub = v >> 2, qt = v & 3;
        const int rb = sub >> 1, kt = sub & 1;
        const char* src =
            w8 + ((size_t)((nt * 2 + rb) * 128 + k64b + t2 * 2 + kt) << 12) +
            qt * 1024 + (size_t)l * 16;
        GLDS16(src, &lds[tb][32768 + (rb * 2 + kt) * 4096 + qt * 1024]);
      }
    }
  };

  auto read_frags = [&](int cur, int kt, v4i (&af)[4], v4i (&bq)[4]) {
#pragma unroll
    for (int i = 0; i < 4; ++i) {
      const int ra = wm + i * 16 + l15;  // 0..255
      af[i] = *(const v4i*)&lds[cur][((ra >> 6) * 2 + kt) * 4096 +
                                     swb(ra & 63, q)];
    }
#pragma unroll
    for (int j = 0; j < 4; ++j) {
      const int rb = wn + j * 16 + l15;  // 0..127
      bq[j] = *(const v4i*)&lds[cur][32768 + ((rb >> 6) * 2 + kt) * 4096 +
                                     swb(rb & 63, q)];
    }
  };

  // prologue: K-tiles 0,1 fully staged -> 12 glds/wave in flight
  stage_half(0, 0, 0);
  stage_half(0, 0, 1);
  stage_half(1, 1, 0);
  stage_half(1, 1, 1);

#pragma unroll 1
  for (int tt = 0; tt < NKT; ++tt) {
    const int cur = tt % 3;
    const int tgt = (tt + 2) % 3;

    // ---- phase 0 (k64 half 0) ----
    SB;
    if (tt + 1 < NKT)
      asm volatile("s_waitcnt vmcnt(6)" ::: "memory");  // K-tile tt landed
    else
      asm volatile("s_waitcnt vmcnt(0)" ::: "memory");
    SB;
    __builtin_amdgcn_s_barrier();
    SB;
    {
      v4i af[4], bq[4];
      read_frags(cur, 0, af, bq);
      if (tt + 2 < NKT) stage_half(tt + 2, tgt, 0);
      asm volatile("s_waitcnt lgkmcnt(0)" ::: "memory");
      SB;  // rule 18: pin MFMA after the wait
      __builtin_amdgcn_s_setprio(1);
#pragma unroll
      for (int i = 0; i < 4; ++i)
#pragma unroll
        for (int j = 0; j < 4; ++j)
          acc[i][j] = __builtin_amdgcn_mfma_i32_16x16x64_i8(af[i], bq[j],
                                                            acc[i][j], 0, 0, 0);
      __builtin_amdgcn_s_setprio(0);
    }

    // ---- phase 1 (k64 half 1) ----
    SB;
    __builtin_amdgcn_s_barrier();
    SB;
    {
      v4i af[4], bq[4];
      read_frags(cur, 1, af, bq);
      if (tt + 2 < NKT) stage_half(tt + 2, tgt, 1);
      asm volatile("s_waitcnt lgkmcnt(0)" ::: "memory");
      SB;
      __builtin_amdgcn_s_setprio(1);
#pragma unroll
      for (int i = 0; i < 4; ++i)
#pragma unroll
        for (int j = 0; j < 4; ++j)
          acc[i][j] = __builtin_amdgcn_mfma_i32_16x16x64_i8(af[i], bq[j],
                                                            acc[i][j], 0, 0, 0);
      __builtin_amdgcn_s_setprio(0);
    }

    // scale-fold: this K-tile == one (n128,k128) scale block
    const float sc = wsc[nt * 64 + kh * NKT + tt];
#pragma unroll
    for (int i = 0; i < 4; ++i)
#pragma unroll
      for (int j = 0; j < 4; ++j) {
#pragma unroll
        for (int r = 0; r < 4; ++r)
          facc[i][j][r] = fmaf(sc, (float)acc[i][j][r], facc[i][j][r]);
        acc[i][j] = v4i{0, 0, 0, 0};
      }
  }

  float* dst = outp + ((KS > 1) ? (size_t)kh * MDIM * NDIM : 0);
#pragma unroll
  for (int i = 0; i < 4; ++i) {
    const int mrow = mt * 256 + wm + i * 16 + q * 4;
#pragma unroll
    for (int j = 0; j < 4; ++j) {
      const int ocol = nt * 128 + wn + j * 16 + l15;
#pragma unroll
      for (int r = 0; r < 4; ++r)
        dst[(size_t)(mrow + r) * NDIM + ocol] = ax[mrow + r] * facc[i][j][r];
    }
  }
}

extern "C" void kernel_launch(void* const* d_in, const int* in_sizes, int n_in,
                              void* d_out, int out_size, void* d_ws,
                              size_t ws_size, hipStream_t stream) {
  const float* x = (const float*)d_in[0];
  const int* wq = (const int*)d_in[1];
  const float* wsc = (const float*)d_in[2];
  float* out = (float*)d_out;

  const size_t W8 = (size_t)NDIM * KDIM;      // 64 MB
  const size_t XQ = (size_t)MDIM * KDIM;      // 4 MB
  const size_t AX = 65536;                    // padded
  const size_t PS = (size_t)MDIM * NDIM * 4;  // 16 MB per partial

  char* w8 = (char*)d_ws;
  char* xq = (char*)d_ws + W8;
  float* ax = (float*)((char*)d_ws + W8 + XQ);
  float* part = (float*)((char*)d_ws + W8 + XQ + AX);

  produce_kernel<<<dim3(16384 + MDIM), dim3(256), 0, stream>>>(wq, x, w8, xq, ax);

  if (ws_size >= W8 + XQ + AX + 2 * PS) {
    gemm_i8_kernel<2><<<dim3(256), dim3(512), 0, stream>>>(xq, w8, wsc, ax, part);
    reduce_kernel<2><<<dim3((MDIM * NDIM) / (256 * 4)), dim3(256), 0, stream>>>(part, out);
  } else {
    gemm_i8_kernel<1><<<dim3(128), dim3(512), 0, stream>>>(xq, w8, wsc, ax, out);
  }
}